// Round 3
// baseline (139.460 us; speedup 1.0000x reference)
//
#include <hip/hip_runtime.h>
#include <stdint.h>

// ContrastiveLossInBatch: loss = mean_i [ lse_j(q_i.k_j/T) - q_i.k_i/T ],
// N=8192, C=256, T=0.07. Fused MFMA GEMM + per-lane online logsumexp (base 2).
//
// R3: R2 hit the 32x32-MFMA floor on the MFMA pipe (MfmaUtil 26% x 51us =
// 13.3us busy = the floor) but wall time was 3.7x the floor: 64 KiB LDS dbuf
// capped residency at 2 blocks/CU = 2 waves/SIMD, so the 16-deep dependent
// MFMA chain + LSE VALU phase + barrier could not be hidden. R3 halves the
// tile (BN=32 -> 16 KiB, dbuf 32 KiB) and doubles the grid (SPLIT=16, 1024
// blocks) -> 4 blocks/CU = 4 waves/SIMD. LDS traffic and MFMA work unchanged;
// only wave-level parallelism rises. VGPR budget: a=64 + M/S=32 + acc=16 +
// temps ~ 124 <= 128 cap (launch_bounds(256,4)); single acc chain, one B temp.
//
// Workspace layout (9.03 MiB):
//   [0,       4 MiB)  q in f16, pre-scaled by (1/T)*log2(e)
//   [4 MiB,   8 MiB)  k in f16
//   [8 MiB, +512 KiB) per-(split,row) running max M   (SPLIT*N floats)
//   ...     +512 KiB  per-(split,row) running sum S
//   ...     +32 KiB   per-row diagonal (base-2 units)
//   ...               32 partial row-loss sums

#define N_ROWS 8192
#define C_DIM  256
#define BN     32
#define SPLIT  16
#define JCOLS  (N_ROWS / SPLIT)   // 512 columns per split
#define JTILES (JCOLS / BN)       // 16 k-tiles per block
#define BLK_ROWS 128              // 4 waves * 32 rows
#define TILE_B  (BN * C_DIM * 2)  // 16 KiB per k-tile

typedef __attribute__((ext_vector_type(8)))  _Float16 half8;
typedef __attribute__((ext_vector_type(4)))  _Float16 half4;
typedef __attribute__((ext_vector_type(16))) float    f32x16;

#if __has_builtin(__builtin_amdgcn_exp2f)
#define EXP2(x) __builtin_amdgcn_exp2f(x)
#else
#define EXP2(x) exp2f(x)
#endif
#if __has_builtin(__builtin_amdgcn_logf)
#define LOG2(x) __builtin_amdgcn_logf(x)
#else
#define LOG2(x) log2f(x)
#endif

__device__ __forceinline__ void gload_lds16(const void* g, void* l) {
  __builtin_amdgcn_global_load_lds(
      (const __attribute__((address_space(1))) unsigned int*)g,
      (__attribute__((address_space(3))) unsigned int*)l, 16, 0, 0);
}

// ---- fp32 -> f16 conversion + per-row diagonal -----------------------------
// One wave covers exactly one row (64 lanes x 4 elems = 256 = C), so the
// diagonal q_i.k_i (f16-rounded operands, f32 accum) is a free wave-reduce.
__global__ void cvt_kernel(const float* __restrict__ q, const float* __restrict__ k,
                           _Float16* __restrict__ qh, _Float16* __restrict__ kh,
                           float* __restrict__ pP) {
  const float QS = 20.60992915555663f;  // (1/0.07) * log2(e)
  int i = blockIdx.x * 256 + threadIdx.x;
  float4 qv = ((const float4*)q)[i];
  float4 kv = ((const float4*)k)[i];
  half4 qo, ko;
  qo[0] = (_Float16)(qv.x * QS); qo[1] = (_Float16)(qv.y * QS);
  qo[2] = (_Float16)(qv.z * QS); qo[3] = (_Float16)(qv.w * QS);
  ko[0] = (_Float16)kv.x; ko[1] = (_Float16)kv.y;
  ko[2] = (_Float16)kv.z; ko[3] = (_Float16)kv.w;
  ((half4*)qh)[i] = qo;
  ((half4*)kh)[i] = ko;

  float d = (float)qo[0] * (float)ko[0];
  d = fmaf((float)qo[1], (float)ko[1], d);
  d = fmaf((float)qo[2], (float)ko[2], d);
  d = fmaf((float)qo[3], (float)ko[3], d);
#pragma unroll
  for (int off = 1; off < 64; off <<= 1) d += __shfl_xor(d, off);
  if ((threadIdx.x & 63) == 0) pP[i >> 6] = d;   // row = global_thread / 64
}

// ---- main fused GEMM + per-lane online base-2 logsumexp --------------------
// Block: 256 threads = 4 waves; wave owns 32 rows via 32x32x16 MFMA.
// A layout: lane l holds q[row0 + (l&31)][ks*16 + (l>>5)*8 .. +8).
// B layout: lane l holds k[j0 + (l&31)][ks*16 + (l>>5)*8 .. +8).
// C/D layout (verified m74/m101): col = lane&31, row = (j&3)+8*(j>>2)+4*(l>>5).
// k-tile (32x256 f16 = 16 KiB) double-buffered; XOR-swizzled (16B chunk
// c at row r lives at slot c^r) -> conflict-free ds_read_b128.
__launch_bounds__(256, 4)
__global__ void sim_lse_kernel(const _Float16* __restrict__ qh,
                               const _Float16* __restrict__ kh,
                               float* __restrict__ pM,
                               float* __restrict__ pS) {
  __shared__ __align__(16) _Float16 kt[2 * BN * C_DIM];  // 32 KiB (2 buffers)
  const int tid  = threadIdx.x;
  const int lane = tid & 63;
  const int wave = tid >> 6;
  const int r    = lane & 31;
  const int hi   = lane >> 5;

  const int bid  = blockIdx.x;
  const int sp   = bid & (SPLIT - 1);
  const int rb   = bid >> 4;
  const int row0 = rb * BLK_ROWS + wave * 32;

  // A fragments resident for whole kernel: 16 x half8 = 64 VGPR
  half8 a[16];
  {
    const _Float16* qr = qh + (size_t)(row0 + r) * C_DIM + hi * 8;
#pragma unroll
    for (int ks = 0; ks < 16; ++ks) a[ks] = *(const half8*)(qr + ks * 16);
  }

  // Per-lane LSE state over this lane's 16 output rows (col = tile col r)
  float M[16], S[16];
#pragma unroll
  for (int j = 0; j < 16; ++j) { M[j] = -__builtin_inff(); S[j] = 0.f; }

  // swizzled read base; addr = bb ^ (ks*32) yields chunk (2ks|hi)^r at row r
  const int bb = r * 512 + ((hi ^ r) << 4);

  const char* ksrc = (const char*)(kh + (size_t)sp * JCOLS * C_DIM);
  char* lds = (char*)kt;

  // ---- prologue: stage tile 0 into buffer 0 (swizzled source, linear dest)
#pragma unroll
  for (int it = 0; it < 4; ++it) {
    int linear = it * 4096 + tid * 16;
    int row = linear >> 9;                      // 512 B per k row
    int gc  = ((linear >> 4) & 31) ^ row;
    gload_lds16(ksrc + row * 512 + gc * 16, lds + linear);
  }

  for (int jt = 0; jt < JTILES; ++jt) {
    __syncthreads();  // own vmcnt drained before barrier => tile jt staged;
                      // prev tile's lgkm reads drained => other buffer free
    const char* cur = lds + (jt & 1) * TILE_B;

    // issue next tile's loads NOW; they land during compute below
    if (jt + 1 < JTILES) {
      const char* src = ksrc + (size_t)(jt + 1) * TILE_B;
      char* nxt = lds + ((jt + 1) & 1) * TILE_B;
#pragma unroll
      for (int it = 0; it < 4; ++it) {
        int linear = it * 4096 + tid * 16;
        int row = linear >> 9;
        int gc  = ((linear >> 4) & 31) ^ row;
        gload_lds16(src + row * 512 + gc * 16, nxt + linear);
      }
    }

    // ---- 32-col tile: 16 K-steps; one B-read feeds 32768 FLOP -------------
    f32x16 acc;
#pragma unroll
    for (int j = 0; j < 16; ++j) acc[j] = 0.f;

#pragma unroll
    for (int ks = 0; ks < 16; ++ks) {
      half8 b = *(const half8*)(cur + (bb ^ (ks * 32)));
      acc = __builtin_amdgcn_mfma_f32_32x32x16_f16(a[ks], b, acc, 0, 0, 0);
    }

    // ---- per-lane online logsumexp (base 2), no cross-lane traffic --------
#pragma unroll
    for (int j = 0; j < 16; ++j) {
      float v = acc[j];
      float newM  = fmaxf(M[j], v);
      float alpha = EXP2(M[j] - newM);        // exp2(-inf)=0 handles init
      float p     = EXP2(v - newM);
      S[j] = fmaf(S[j], alpha, p);
      M[j] = newM;
    }
  }

  // ---- one-time butterfly merge across the 32 lanes of each half ----------
  // Lanes 0..31 (hi=0) hold rows {(j&3)+8*(j>>2)}, lanes 32..63 the +4 rows;
  // offsets 1..16 stay within each 32-lane half.
#pragma unroll
  for (int j = 0; j < 16; ++j) {
#pragma unroll
    for (int off = 1; off < 32; off <<= 1) {
      float Mo = __shfl_xor(M[j], off);
      float So = __shfl_xor(S[j], off);
      float nm = fmaxf(M[j], Mo);
      S[j] = S[j] * EXP2(M[j] - nm) + So * EXP2(Mo - nm);
      M[j] = nm;
    }
  }

  if ((lane & 31) == 0) {   // lanes 0 and 32 write disjoint 16-row sets
#pragma unroll
    for (int j = 0; j < 16; ++j) {
      int grow = row0 + (j & 3) + 8 * (j >> 2) + 4 * hi;
      pM[(size_t)sp * N_ROWS + grow] = M[j];
      pS[(size_t)sp * N_ROWS + grow] = S[j];
    }
  }
}

// ---- stage 1: 32 blocks, one thread per row; partial sums -----------------
__global__ void finish1_kernel(const float* __restrict__ pM, const float* __restrict__ pS,
                               const float* __restrict__ pP, float* __restrict__ pPart) {
  const int tid = threadIdx.x;
  const int r = blockIdx.x * 256 + tid;
  float m = -__builtin_inff();
#pragma unroll
  for (int s = 0; s < SPLIT; ++s) m = fmaxf(m, pM[s * N_ROWS + r]);
  float ssum = 0.f;
#pragma unroll
  for (int s = 0; s < SPLIT; ++s)
    ssum = fmaf(pS[s * N_ROWS + r], EXP2(pM[s * N_ROWS + r] - m), ssum);
  float accl = (m + LOG2(ssum)) - pP[r];   // row loss in base-2 units
#pragma unroll
  for (int off = 1; off < 64; off <<= 1) accl += __shfl_xor(accl, off);
  __shared__ float wsum[4];
  if ((tid & 63) == 0) wsum[tid >> 6] = accl;
  __syncthreads();
  if (tid == 0)
    pPart[blockIdx.x] = wsum[0] + wsum[1] + wsum[2] + wsum[3];
}

// ---- stage 2: reduce 32 partials, convert base-2 -> nats, mean ------------
__global__ void finish2_kernel(const float* __restrict__ pPart, float* __restrict__ out) {
  const int tid = threadIdx.x;   // 64 threads
  float v = (tid < 32) ? pPart[tid] : 0.f;
#pragma unroll
  for (int off = 1; off < 64; off <<= 1) v += __shfl_xor(v, off);
  if (tid == 0)
    out[0] = v * (0.69314718055994531f / (float)N_ROWS);  // ln2 * mean
}

extern "C" void kernel_launch(void* const* d_in, const int* in_sizes, int n_in,
                              void* d_out, int out_size, void* d_ws, size_t ws_size,
                              hipStream_t stream) {
  const float* q = (const float*)d_in[0];
  const float* k = (const float*)d_in[1];
  float* out = (float*)d_out;
  char* ws = (char*)d_ws;

  _Float16* qh = (_Float16*)ws;                                  // 4 MiB
  _Float16* kh = (_Float16*)(ws + (size_t)N_ROWS * C_DIM * 2);   // 4 MiB
  float* pM = (float*)(ws + (size_t)N_ROWS * C_DIM * 4);         // 512 KiB
  float* pS = pM + SPLIT * N_ROWS;                               // 512 KiB
  float* pP = pS + SPLIT * N_ROWS;                               // 32 KiB
  float* pPart = pP + N_ROWS;                                    // 128 B

  cvt_kernel<<<dim3(N_ROWS * C_DIM / 4 / 256), dim3(256), 0, stream>>>(q, k, qh, kh, pP);
  sim_lse_kernel<<<dim3((N_ROWS / BLK_ROWS) * SPLIT), dim3(256), 0, stream>>>(qh, kh, pM, pS);
  finish1_kernel<<<dim3(N_ROWS / 256), dim3(256), 0, stream>>>(pM, pS, pP, pPart);
  finish2_kernel<<<dim3(1), dim3(64), 0, stream>>>(pPart, out);
}

// Round 5
// 125.461 us; speedup vs baseline: 1.1116x; 1.1116x over previous
//
#include <hip/hip_runtime.h>
#include <stdint.h>

// ContrastiveLossInBatch: loss = mean_i [ lse_j(q_i.k_j/T) - q_i.k_i/T ],
// N=8192, C=256, T=0.07. Fused MFMA GEMM + per-lane online logsumexp (base 2).
//
// R5: R4's operand-swap (mfma(k,q)) produced NaN; the q-row attribution under
// swap rides on the B-operand n<->lane mapping, which our tests CANNOT verify
// (row-LSE is column-permutation invariant) -> reverted to the R2-verified
// orientation and store mapping. Occupancy fix instead comes from the cap:
// R2 measured the true arch-register demand (104 VGPR, no spill, cap 256);
// R3 proved cap 128 too tight (allocator split 64/64 -> 24 MB scratch).
// launch_bounds(256,3) sets cap ~170: holds the 104-reg demand, LDS 32 KiB
// dbuf allows 5 blocks/CU -> VGPR-limited 3 blocks/CU = 12 waves/CU (1.5x
// R2). Geometry stays R3's verified BN=32 / SPLIT=16 / 1024 blocks.
//
// Workspace layout (9.03 MiB):
//   [0,       4 MiB)  q in f16, pre-scaled by (1/T)*log2(e)
//   [4 MiB,   8 MiB)  k in f16
//   [8 MiB, +512 KiB) per-(split,row) running max M   (SPLIT*N floats)
//   ...     +512 KiB  per-(split,row) running sum S
//   ...     +32 KiB   per-row diagonal (base-2 units)
//   ...               32 partial row-loss sums

#define N_ROWS 8192
#define C_DIM  256
#define BN     32
#define SPLIT  16
#define JCOLS  (N_ROWS / SPLIT)   // 512 columns per split
#define JTILES (JCOLS / BN)       // 16 k-tiles per block
#define BLK_ROWS 128              // 4 waves * 32 rows
#define TILE_B  (BN * C_DIM * 2)  // 16 KiB per k-tile

typedef __attribute__((ext_vector_type(8)))  _Float16 half8;
typedef __attribute__((ext_vector_type(4)))  _Float16 half4;
typedef __attribute__((ext_vector_type(16))) float    f32x16;

#if __has_builtin(__builtin_amdgcn_exp2f)
#define EXP2(x) __builtin_amdgcn_exp2f(x)
#else
#define EXP2(x) exp2f(x)
#endif
#if __has_builtin(__builtin_amdgcn_logf)
#define LOG2(x) __builtin_amdgcn_logf(x)
#else
#define LOG2(x) log2f(x)
#endif

__device__ __forceinline__ void gload_lds16(const void* g, void* l) {
  __builtin_amdgcn_global_load_lds(
      (const __attribute__((address_space(1))) unsigned int*)g,
      (__attribute__((address_space(3))) unsigned int*)l, 16, 0, 0);
}

// ---- fp32 -> f16 conversion + per-row diagonal -----------------------------
// One wave covers exactly one row (64 lanes x 4 elems = 256 = C), so the
// diagonal q_i.k_i (f16-rounded operands, f32 accum) is a free wave-reduce.
__global__ void cvt_kernel(const float* __restrict__ q, const float* __restrict__ k,
                           _Float16* __restrict__ qh, _Float16* __restrict__ kh,
                           float* __restrict__ pP) {
  const float QS = 20.60992915555663f;  // (1/0.07) * log2(e)
  int i = blockIdx.x * 256 + threadIdx.x;
  float4 qv = ((const float4*)q)[i];
  float4 kv = ((const float4*)k)[i];
  half4 qo, ko;
  qo[0] = (_Float16)(qv.x * QS); qo[1] = (_Float16)(qv.y * QS);
  qo[2] = (_Float16)(qv.z * QS); qo[3] = (_Float16)(qv.w * QS);
  ko[0] = (_Float16)kv.x; ko[1] = (_Float16)kv.y;
  ko[2] = (_Float16)kv.z; ko[3] = (_Float16)kv.w;
  ((half4*)qh)[i] = qo;
  ((half4*)kh)[i] = ko;

  float d = (float)qo[0] * (float)ko[0];
  d = fmaf((float)qo[1], (float)ko[1], d);
  d = fmaf((float)qo[2], (float)ko[2], d);
  d = fmaf((float)qo[3], (float)ko[3], d);
#pragma unroll
  for (int off = 1; off < 64; off <<= 1) d += __shfl_xor(d, off);
  if ((threadIdx.x & 63) == 0) pP[i >> 6] = d;   // row = global_thread / 64
}

// ---- main fused GEMM + per-lane online base-2 logsumexp --------------------
// Block: 256 threads = 4 waves; wave owns 32 rows via 32x32x16 MFMA.
// A layout: lane l holds q[row0 + (l&31)][ks*16 + (l>>5)*8 .. +8).
// B layout: lane l holds k[j0 + (l&31)][ks*16 + (l>>5)*8 .. +8).
// C/D layout (verified m74/m101 + R2 pass): col = lane&31,
// row = (j&3)+8*(j>>2)+4*(l>>5).
// k-tile (32x256 f16 = 16 KiB) double-buffered; XOR-swizzled (16B chunk
// c at row r lives at slot c^r) -> conflict-free ds_read_b128.
__launch_bounds__(256, 3)
__global__ void sim_lse_kernel(const _Float16* __restrict__ qh,
                               const _Float16* __restrict__ kh,
                               float* __restrict__ pM,
                               float* __restrict__ pS) {
  __shared__ __align__(16) _Float16 kt[2 * BN * C_DIM];  // 32 KiB (2 buffers)
  const int tid  = threadIdx.x;
  const int lane = tid & 63;
  const int wave = tid >> 6;
  const int r    = lane & 31;
  const int hi   = lane >> 5;

  const int bid  = blockIdx.x;
  const int sp   = bid & (SPLIT - 1);
  const int rb   = bid >> 4;
  const int row0 = rb * BLK_ROWS + wave * 32;

  // A fragments resident for whole kernel: 16 x half8 = 64 VGPR
  half8 a[16];
  {
    const _Float16* qr = qh + (size_t)(row0 + r) * C_DIM + hi * 8;
#pragma unroll
    for (int ks = 0; ks < 16; ++ks) a[ks] = *(const half8*)(qr + ks * 16);
  }

  // Per-lane LSE state over this lane's 16 output rows (col = tile col r)
  float M[16], S[16];
#pragma unroll
  for (int j = 0; j < 16; ++j) { M[j] = -__builtin_inff(); S[j] = 0.f; }

  // swizzled read base; addr = bb ^ (ks*32) yields chunk (2ks|hi)^r at row r
  const int bb = r * 512 + ((hi ^ r) << 4);

  const char* ksrc = (const char*)(kh + (size_t)sp * JCOLS * C_DIM);
  char* lds = (char*)kt;

  // ---- prologue: stage tile 0 into buffer 0 (swizzled source, linear dest)
#pragma unroll
  for (int it = 0; it < 4; ++it) {
    int linear = it * 4096 + tid * 16;
    int row = linear >> 9;                      // 512 B per k row
    int gc  = ((linear >> 4) & 31) ^ row;
    gload_lds16(ksrc + row * 512 + gc * 16, lds + linear);
  }

  for (int jt = 0; jt < JTILES; ++jt) {
    __syncthreads();  // own vmcnt drained before barrier => tile jt staged;
                      // prev tile's lgkm reads drained => other buffer free
    const char* cur = lds + (jt & 1) * TILE_B;

    // issue next tile's loads NOW; they land during compute below
    if (jt + 1 < JTILES) {
      const char* src = ksrc + (size_t)(jt + 1) * TILE_B;
      char* nxt = lds + ((jt + 1) & 1) * TILE_B;
#pragma unroll
      for (int it = 0; it < 4; ++it) {
        int linear = it * 4096 + tid * 16;
        int row = linear >> 9;
        int gc  = ((linear >> 4) & 31) ^ row;
        gload_lds16(src + row * 512 + gc * 16, nxt + linear);
      }
    }

    // ---- 32-col tile: 16 K-steps; one B-read feeds 32768 FLOP -------------
    f32x16 acc;
#pragma unroll
    for (int j = 0; j < 16; ++j) acc[j] = 0.f;

#pragma unroll
    for (int ks = 0; ks < 16; ++ks) {
      half8 b = *(const half8*)(cur + (bb ^ (ks * 32)));
      acc = __builtin_amdgcn_mfma_f32_32x32x16_f16(a[ks], b, acc, 0, 0, 0);
    }

    // ---- per-lane online logsumexp (base 2), no cross-lane traffic --------
#pragma unroll
    for (int j = 0; j < 16; ++j) {
      float v = acc[j];
      float newM  = fmaxf(M[j], v);
      float alpha = EXP2(M[j] - newM);        // exp2(-inf)=0 handles init
      float p     = EXP2(v - newM);
      S[j] = fmaf(S[j], alpha, p);
      M[j] = newM;
    }
  }

  // ---- one-time butterfly merge across the 32 lanes of each half ----------
  // Lanes 0..31 (hi=0) hold rows {(j&3)+8*(j>>2)}, lanes 32..63 the +4 rows;
  // offsets 1..16 stay within each 32-lane half.
#pragma unroll
  for (int j = 0; j < 16; ++j) {
#pragma unroll
    for (int off = 1; off < 32; off <<= 1) {
      float Mo = __shfl_xor(M[j], off);
      float So = __shfl_xor(S[j], off);
      float nm = fmaxf(M[j], Mo);
      S[j] = S[j] * EXP2(M[j] - nm) + So * EXP2(Mo - nm);
      M[j] = nm;
    }
  }

  if ((lane & 31) == 0) {   // lanes 0 and 32 write disjoint 16-row sets
#pragma unroll
    for (int j = 0; j < 16; ++j) {
      int grow = row0 + (j & 3) + 8 * (j >> 2) + 4 * hi;
      pM[(size_t)sp * N_ROWS + grow] = M[j];
      pS[(size_t)sp * N_ROWS + grow] = S[j];
    }
  }
}

// ---- stage 1: 32 blocks, one thread per row; partial sums -----------------
__global__ void finish1_kernel(const float* __restrict__ pM, const float* __restrict__ pS,
                               const float* __restrict__ pP, float* __restrict__ pPart) {
  const int tid = threadIdx.x;
  const int r = blockIdx.x * 256 + tid;
  float m = -__builtin_inff();
#pragma unroll
  for (int s = 0; s < SPLIT; ++s) m = fmaxf(m, pM[s * N_ROWS + r]);
  float ssum = 0.f;
#pragma unroll
  for (int s = 0; s < SPLIT; ++s)
    ssum = fmaf(pS[s * N_ROWS + r], EXP2(pM[s * N_ROWS + r] - m), ssum);
  float accl = (m + LOG2(ssum)) - pP[r];   // row loss in base-2 units
#pragma unroll
  for (int off = 1; off < 64; off <<= 1) accl += __shfl_xor(accl, off);
  __shared__ float wsum[4];
  if ((tid & 63) == 0) wsum[tid >> 6] = accl;
  __syncthreads();
  if (tid == 0)
    pPart[blockIdx.x] = wsum[0] + wsum[1] + wsum[2] + wsum[3];
}

// ---- stage 2: reduce 32 partials, convert base-2 -> nats, mean ------------
__global__ void finish2_kernel(const float* __restrict__ pPart, float* __restrict__ out) {
  const int tid = threadIdx.x;   // 64 threads
  float v = (tid < 32) ? pPart[tid] : 0.f;
#pragma unroll
  for (int off = 1; off < 64; off <<= 1) v += __shfl_xor(v, off);
  if (tid == 0)
    out[0] = v * (0.69314718055994531f / (float)N_ROWS);  // ln2 * mean
}

extern "C" void kernel_launch(void* const* d_in, const int* in_sizes, int n_in,
                              void* d_out, int out_size, void* d_ws, size_t ws_size,
                              hipStream_t stream) {
  const float* q = (const float*)d_in[0];
  const float* k = (const float*)d_in[1];
  float* out = (float*)d_out;
  char* ws = (char*)d_ws;

  _Float16* qh = (_Float16*)ws;                                  // 4 MiB
  _Float16* kh = (_Float16*)(ws + (size_t)N_ROWS * C_DIM * 2);   // 4 MiB
  float* pM = (float*)(ws + (size_t)N_ROWS * C_DIM * 4);         // 512 KiB
  float* pS = pM + SPLIT * N_ROWS;                               // 512 KiB
  float* pP = pS + SPLIT * N_ROWS;                               // 32 KiB
  float* pPart = pP + N_ROWS;                                    // 128 B

  cvt_kernel<<<dim3(N_ROWS * C_DIM / 4 / 256), dim3(256), 0, stream>>>(q, k, qh, kh, pP);
  sim_lse_kernel<<<dim3((N_ROWS / BLK_ROWS) * SPLIT), dim3(256), 0, stream>>>(qh, kh, pM, pS);
  finish1_kernel<<<dim3(N_ROWS / 256), dim3(256), 0, stream>>>(pM, pS, pP, pPart);
  finish2_kernel<<<dim3(1), dim3(64), 0, stream>>>(pPart, out);
}

// Round 6
// 112.630 us; speedup vs baseline: 1.2382x; 1.1139x over previous
//
#include <hip/hip_runtime.h>
#include <stdint.h>

// ContrastiveLossInBatch: loss = mean_i [ lse_j(q_i.k_j/T) - q_i.k_i/T ],
// N=8192, C=256, T=0.07. Fused MFMA GEMM + per-lane online logsumexp (base 2).
//
// R6: allocator model from R3/R5: under launch_bounds pressure the backend
// splits the unified VGPR file ~in half (arch = cap/2: 64@cap128, 84@cap170)
// regardless of accum need -> spill + scratch-capped occupancy. Fix = cut
// TRUE demand below 128 at cap 256. The 32x32 orientation needs M/S[16]=32
// regs (irreducible). Revert to the R0-harness-verified 16x16x32 structure
// with RF=2 row-frags: per-lane slots = 2 rf x 4 j = 8 rows, and the two
// col-frags of each row merge online -> M/S = 16 regs. Per 16B B-read: 2
// MFMAs (LDS traffic unchanged vs 32x32). Demand ~ a(64)+MS(16)+acc(16)+
// temps ~ 120 <= 128 -> 4 waves/SIMD from ACTUAL usage, launch_bounds(256,2)
// (no cap pressure). All fragment/swizzle/store mappings verbatim from R0.
//
// Workspace layout (9.03 MiB):
//   [0,       4 MiB)  q in f16, pre-scaled by (1/T)*log2(e)
//   [4 MiB,   8 MiB)  k in f16
//   [8 MiB, +512 KiB) per-(split,row) running max M   (SPLIT*N floats)
//   ...     +512 KiB  per-(split,row) running sum S
//   ...     +32 KiB   per-row diagonal (base-2 units)
//   ...               32 partial row-loss sums

#define N_ROWS 8192
#define C_DIM  256
#define BN     32
#define SPLIT  16
#define JCOLS  (N_ROWS / SPLIT)   // 512 columns per split
#define JTILES (JCOLS / BN)       // 16 k-tiles per block
#define BLK_ROWS 128              // 4 waves * 32 rows
#define TILE_B  (BN * C_DIM * 2)  // 16 KiB per k-tile

typedef __attribute__((ext_vector_type(8)))  _Float16 half8;
typedef __attribute__((ext_vector_type(4)))  _Float16 half4;
typedef __attribute__((ext_vector_type(4)))  float    f32x4;

#if __has_builtin(__builtin_amdgcn_exp2f)
#define EXP2(x) __builtin_amdgcn_exp2f(x)
#else
#define EXP2(x) exp2f(x)
#endif
#if __has_builtin(__builtin_amdgcn_logf)
#define LOG2(x) __builtin_amdgcn_logf(x)
#else
#define LOG2(x) log2f(x)
#endif

__device__ __forceinline__ void gload_lds16(const void* g, void* l) {
  __builtin_amdgcn_global_load_lds(
      (const __attribute__((address_space(1))) unsigned int*)g,
      (__attribute__((address_space(3))) unsigned int*)l, 16, 0, 0);
}

// ---- fp32 -> f16 conversion + per-row diagonal -----------------------------
// One wave covers exactly one row (64 lanes x 4 elems = 256 = C), so the
// diagonal q_i.k_i (f16-rounded operands, f32 accum) is a free wave-reduce.
__global__ void cvt_kernel(const float* __restrict__ q, const float* __restrict__ k,
                           _Float16* __restrict__ qh, _Float16* __restrict__ kh,
                           float* __restrict__ pP) {
  const float QS = 20.60992915555663f;  // (1/0.07) * log2(e)
  int i = blockIdx.x * 256 + threadIdx.x;
  float4 qv = ((const float4*)q)[i];
  float4 kv = ((const float4*)k)[i];
  half4 qo, ko;
  qo[0] = (_Float16)(qv.x * QS); qo[1] = (_Float16)(qv.y * QS);
  qo[2] = (_Float16)(qv.z * QS); qo[3] = (_Float16)(qv.w * QS);
  ko[0] = (_Float16)kv.x; ko[1] = (_Float16)kv.y;
  ko[2] = (_Float16)kv.z; ko[3] = (_Float16)kv.w;
  ((half4*)qh)[i] = qo;
  ((half4*)kh)[i] = ko;

  float d = (float)qo[0] * (float)ko[0];
  d = fmaf((float)qo[1], (float)ko[1], d);
  d = fmaf((float)qo[2], (float)ko[2], d);
  d = fmaf((float)qo[3], (float)ko[3], d);
#pragma unroll
  for (int off = 1; off < 64; off <<= 1) d += __shfl_xor(d, off);
  if ((threadIdx.x & 63) == 0) pP[i >> 6] = d;   // row = global_thread / 64
}

// ---- main fused GEMM + per-lane online base-2 logsumexp --------------------
// Block: 256 threads = 4 waves; wave owns 32 rows as 2 x 16-row fragments
// (16x16x32 MFMA, R0-verified mappings):
//  A: lane holds q[row0 + rf*16 + l15][ks*32 + lg*8 .. +8)
//  B: lane holds k[j0  + cf*16 + l15][ks*32 + lg*8 .. +8)
//  C/D: col = cf*16 + l15, row = row0 + rf*16 + lg*4 + j   (harness-verified)
// One B-read feeds both rf MFMAs; both cf values of a row merge online ->
// 8 (M,S) slots/lane. k-tile (32x256 f16 = 16 KiB) double-buffered,
// XOR-swizzled (R0 formulas) -> conflict-free ds_read_b128.
__launch_bounds__(256, 2)
__global__ void sim_lse_kernel(const _Float16* __restrict__ qh,
                               const _Float16* __restrict__ kh,
                               float* __restrict__ pM,
                               float* __restrict__ pS) {
  __shared__ __align__(16) _Float16 kt[2 * BN * C_DIM];  // 32 KiB (2 buffers)
  const int tid  = threadIdx.x;
  const int lane = tid & 63;
  const int wave = tid >> 6;
  const int l15  = lane & 15;
  const int lg   = lane >> 4;       // quad group 0..3

  const int bid  = blockIdx.x;
  const int sp   = bid & (SPLIT - 1);
  const int rb   = bid >> 4;
  const int row0 = rb * BLK_ROWS + wave * 32;

  // A fragments resident for whole kernel: 2 x 8 x half8 = 64 VGPR
  half8 a[2][8];
#pragma unroll
  for (int rf = 0; rf < 2; ++rf) {
    const _Float16* qr = qh + (size_t)(row0 + rf * 16 + l15) * C_DIM + lg * 8;
#pragma unroll
    for (int ks = 0; ks < 8; ++ks) a[rf][ks] = *(const half8*)(qr + ks * 32);
  }

  // Per-lane LSE state: slot s = rf*4 + j  ->  row = row0 + rf*16 + lg*4 + j,
  // columns {cf*16 + l15 : cf} merged online each tile.
  float M[8], S[8];
#pragma unroll
  for (int s = 0; s < 8; ++s) { M[s] = -__builtin_inff(); S[s] = 0.f; }

  // swizzled LDS read base per col-frag (R0-verified): read bb ^ (ks*64)
  const int nl0 = l15;            // cf = 0
  const int nl1 = 16 + l15;       // cf = 1
  const int bb0 = nl0 * 512 + (((nl0 & 31) * 16) ^ (lg * 16));
  const int bb1 = nl1 * 512 + (((nl1 & 31) * 16) ^ (lg * 16));

  const char* ksrc = (const char*)(kh + (size_t)sp * JCOLS * C_DIM);
  char* lds = (char*)kt;

  // ---- prologue: stage tile 0 into buffer 0 (swizzled source, linear dest)
#pragma unroll
  for (int it = 0; it < 4; ++it) {
    int linear = it * 4096 + tid * 16;
    int row = linear >> 9;                      // 512 B per k row
    int gc  = ((linear >> 4) & 31) ^ (row & 31);
    gload_lds16(ksrc + row * 512 + gc * 16, lds + linear);
  }

  for (int jt = 0; jt < JTILES; ++jt) {
    __syncthreads();  // own vmcnt drained before barrier => tile jt staged;
                      // prev tile's lgkm reads drained => other buffer free
    const char* cur = lds + (jt & 1) * TILE_B;

    // issue next tile's loads NOW; they land during compute below
    if (jt + 1 < JTILES) {
      const char* src = ksrc + (size_t)(jt + 1) * TILE_B;
      char* nxt = lds + ((jt + 1) & 1) * TILE_B;
#pragma unroll
      for (int it = 0; it < 4; ++it) {
        int linear = it * 4096 + tid * 16;
        int row = linear >> 9;
        int gc  = ((linear >> 4) & 31) ^ (row & 31);
        gload_lds16(src + row * 512 + gc * 16, nxt + linear);
      }
    }

    // ---- 32-col tile: 8 K-steps x {2 col-frags x 2 row-frags} MFMA --------
    f32x4 acc00 = {0.f,0.f,0.f,0.f}, acc01 = {0.f,0.f,0.f,0.f};
    f32x4 acc10 = {0.f,0.f,0.f,0.f}, acc11 = {0.f,0.f,0.f,0.f};

#pragma unroll
    for (int ks = 0; ks < 8; ++ks) {
      half8 b0 = *(const half8*)(cur + (bb0 ^ (ks * 64)));
      half8 b1 = *(const half8*)(cur + (bb1 ^ (ks * 64)));
      acc00 = __builtin_amdgcn_mfma_f32_16x16x32_f16(a[0][ks], b0, acc00, 0, 0, 0);
      acc01 = __builtin_amdgcn_mfma_f32_16x16x32_f16(a[0][ks], b1, acc01, 0, 0, 0);
      acc10 = __builtin_amdgcn_mfma_f32_16x16x32_f16(a[1][ks], b0, acc10, 0, 0, 0);
      acc11 = __builtin_amdgcn_mfma_f32_16x16x32_f16(a[1][ks], b1, acc11, 0, 0, 0);
    }

    // ---- per-lane online logsumexp: merge the row's two cols in one step --
#pragma unroll
    for (int j = 0; j < 4; ++j) {
      {  // rf = 0, slot j
        float v0 = acc00[j], v1 = acc01[j];
        float newM  = fmaxf(M[j], fmaxf(v0, v1));
        float alpha = EXP2(M[j] - newM);      // exp2(-inf)=0 handles init
        float p = EXP2(v0 - newM) + EXP2(v1 - newM);
        S[j] = fmaf(S[j], alpha, p);
        M[j] = newM;
      }
      {  // rf = 1, slot 4 + j
        float v0 = acc10[j], v1 = acc11[j];
        float newM  = fmaxf(M[4 + j], fmaxf(v0, v1));
        float alpha = EXP2(M[4 + j] - newM);
        float p = EXP2(v0 - newM) + EXP2(v1 - newM);
        S[4 + j] = fmaf(S[4 + j], alpha, p);
        M[4 + j] = newM;
      }
    }
  }

  // ---- one-time 16-lane butterfly merge of (M,S) --------------------------
#pragma unroll
  for (int s = 0; s < 8; ++s) {
#pragma unroll
    for (int off = 1; off < 16; off <<= 1) {
      float Mo = __shfl_xor(M[s], off);
      float So = __shfl_xor(S[s], off);
      float nm = fmaxf(M[s], Mo);
      S[s] = S[s] * EXP2(M[s] - nm) + So * EXP2(Mo - nm);
      M[s] = nm;
    }
  }

  if (l15 == 0) {   // 4 lanes per wave (lg = 0..3), 8 rows each = 32 rows
#pragma unroll
    for (int s = 0; s < 8; ++s) {
      int grow = row0 + (s >> 2) * 16 + lg * 4 + (s & 3);
      pM[(size_t)sp * N_ROWS + grow] = M[s];
      pS[(size_t)sp * N_ROWS + grow] = S[s];
    }
  }
}

// ---- stage 1: 32 blocks, one thread per row; partial sums -----------------
__global__ void finish1_kernel(const float* __restrict__ pM, const float* __restrict__ pS,
                               const float* __restrict__ pP, float* __restrict__ pPart) {
  const int tid = threadIdx.x;
  const int r = blockIdx.x * 256 + tid;
  float m = -__builtin_inff();
#pragma unroll
  for (int s = 0; s < SPLIT; ++s) m = fmaxf(m, pM[s * N_ROWS + r]);
  float ssum = 0.f;
#pragma unroll
  for (int s = 0; s < SPLIT; ++s)
    ssum = fmaf(pS[s * N_ROWS + r], EXP2(pM[s * N_ROWS + r] - m), ssum);
  float accl = (m + LOG2(ssum)) - pP[r];   // row loss in base-2 units
#pragma unroll
  for (int off = 1; off < 64; off <<= 1) accl += __shfl_xor(accl, off);
  __shared__ float wsum[4];
  if ((tid & 63) == 0) wsum[tid >> 6] = accl;
  __syncthreads();
  if (tid == 0)
    pPart[blockIdx.x] = wsum[0] + wsum[1] + wsum[2] + wsum[3];
}

// ---- stage 2: reduce 32 partials, convert base-2 -> nats, mean ------------
__global__ void finish2_kernel(const float* __restrict__ pPart, float* __restrict__ out) {
  const int tid = threadIdx.x;   // 64 threads
  float v = (tid < 32) ? pPart[tid] : 0.f;
#pragma unroll
  for (int off = 1; off < 64; off <<= 1) v += __shfl_xor(v, off);
  if (tid == 0)
    out[0] = v * (0.69314718055994531f / (float)N_ROWS);  // ln2 * mean
}

extern "C" void kernel_launch(void* const* d_in, const int* in_sizes, int n_in,
                              void* d_out, int out_size, void* d_ws, size_t ws_size,
                              hipStream_t stream) {
  const float* q = (const float*)d_in[0];
  const float* k = (const float*)d_in[1];
  float* out = (float*)d_out;
  char* ws = (char*)d_ws;

  _Float16* qh = (_Float16*)ws;                                  // 4 MiB
  _Float16* kh = (_Float16*)(ws + (size_t)N_ROWS * C_DIM * 2);   // 4 MiB
  float* pM = (float*)(ws + (size_t)N_ROWS * C_DIM * 4);         // 512 KiB
  float* pS = pM + SPLIT * N_ROWS;                               // 512 KiB
  float* pP = pS + SPLIT * N_ROWS;                               // 32 KiB
  float* pPart = pP + N_ROWS;                                    // 128 B

  cvt_kernel<<<dim3(N_ROWS * C_DIM / 4 / 256), dim3(256), 0, stream>>>(q, k, qh, kh, pP);
  sim_lse_kernel<<<dim3((N_ROWS / BLK_ROWS) * SPLIT), dim3(256), 0, stream>>>(qh, kh, pM, pS);
  finish1_kernel<<<dim3(N_ROWS / 256), dim3(256), 0, stream>>>(pM, pS, pP, pPart);
  finish2_kernel<<<dim3(1), dim3(64), 0, stream>>>(pPart, out);
}

// Round 7
// 110.854 us; speedup vs baseline: 1.2580x; 1.0160x over previous
//
#include <hip/hip_runtime.h>
#include <stdint.h>

// ContrastiveLossInBatch: loss = mean_i [ lse_j(q_i.k_j/T) - q_i.k_i/T ],
// N=8192, C=256, T=0.07. Fused MFMA GEMM + per-lane online logsumexp (base 2).
//
// R7: R0/R2/R6 all pin at 48-51us with MfmaUtil ~28% despite 2x LDS-traffic
// differences => LDS BW was never binding. Max-pipe total is ~20us; the ~28us
// gap is the 2-phase barrier structure: __syncthreads emits
// s_waitcnt vmcnt(0) lgkmcnt(0), so each of 16 tiles serializes
// {stage-drain -> ds_read -> MFMA -> LSE} with waves phase-locked (m233's
// measured 2-phase overhead). Fix = T4 counted vmcnt + raw s_barrier:
// triple-buffered 16 KiB tiles, per-iter "vmcnt(4); s_barrier; stage(jt+2);
// compute(jt)". Oldest-first vmcnt retirement (m135) => vmcnt(4) confirms
// stage(jt) landed while stage(jt+1)'s 4 loads stay in flight across the
// barrier. Stage(jt+2) overwrites buf[(jt-1)%3] only after the barrier that
// proves all waves finished reading it. Compute/mappings bit-identical to R6
// (harness-verified).
//
// Workspace layout (9.03 MiB):
//   [0,       4 MiB)  q in f16, pre-scaled by (1/T)*log2(e)
//   [4 MiB,   8 MiB)  k in f16
//   [8 MiB, +512 KiB) per-(split,row) running max M   (SPLIT*N floats)
//   ...     +512 KiB  per-(split,row) running sum S
//   ...     +32 KiB   per-row diagonal (base-2 units)
//   ...               32 partial row-loss sums

#define N_ROWS 8192
#define C_DIM  256
#define BN     32
#define SPLIT  16
#define JCOLS  (N_ROWS / SPLIT)   // 512 columns per split
#define JTILES (JCOLS / BN)       // 16 k-tiles per block
#define BLK_ROWS 128              // 4 waves * 32 rows
#define TILE_B  (BN * C_DIM * 2)  // 16 KiB per k-tile
#define NBUF   3

typedef __attribute__((ext_vector_type(8)))  _Float16 half8;
typedef __attribute__((ext_vector_type(4)))  _Float16 half4;
typedef __attribute__((ext_vector_type(4)))  float    f32x4;

#if __has_builtin(__builtin_amdgcn_exp2f)
#define EXP2(x) __builtin_amdgcn_exp2f(x)
#else
#define EXP2(x) exp2f(x)
#endif
#if __has_builtin(__builtin_amdgcn_logf)
#define LOG2(x) __builtin_amdgcn_logf(x)
#else
#define LOG2(x) log2f(x)
#endif

__device__ __forceinline__ void gload_lds16(const void* g, void* l) {
  __builtin_amdgcn_global_load_lds(
      (const __attribute__((address_space(1))) unsigned int*)g,
      (__attribute__((address_space(3))) unsigned int*)l, 16, 0, 0);
}

// ---- fp32 -> f16 conversion + per-row diagonal -----------------------------
__global__ void cvt_kernel(const float* __restrict__ q, const float* __restrict__ k,
                           _Float16* __restrict__ qh, _Float16* __restrict__ kh,
                           float* __restrict__ pP) {
  const float QS = 20.60992915555663f;  // (1/0.07) * log2(e)
  int i = blockIdx.x * 256 + threadIdx.x;
  float4 qv = ((const float4*)q)[i];
  float4 kv = ((const float4*)k)[i];
  half4 qo, ko;
  qo[0] = (_Float16)(qv.x * QS); qo[1] = (_Float16)(qv.y * QS);
  qo[2] = (_Float16)(qv.z * QS); qo[3] = (_Float16)(qv.w * QS);
  ko[0] = (_Float16)kv.x; ko[1] = (_Float16)kv.y;
  ko[2] = (_Float16)kv.z; ko[3] = (_Float16)kv.w;
  ((half4*)qh)[i] = qo;
  ((half4*)kh)[i] = ko;

  float d = (float)qo[0] * (float)ko[0];
  d = fmaf((float)qo[1], (float)ko[1], d);
  d = fmaf((float)qo[2], (float)ko[2], d);
  d = fmaf((float)qo[3], (float)ko[3], d);
#pragma unroll
  for (int off = 1; off < 64; off <<= 1) d += __shfl_xor(d, off);
  if ((threadIdx.x & 63) == 0) pP[i >> 6] = d;   // row = global_thread / 64
}

// ---- main fused GEMM + per-lane online base-2 logsumexp --------------------
// Block: 256 threads = 4 waves; wave owns 32 rows as 2 x 16-row fragments
// (16x16x32 MFMA, R0/R6-harness-verified mappings):
//  A: lane holds q[row0 + rf*16 + l15][ks*32 + lg*8 .. +8)
//  B: lane holds k[j0  + cf*16 + l15][ks*32 + lg*8 .. +8)
//  C/D: col = cf*16 + l15, row = row0 + rf*16 + lg*4 + j
// One B-read feeds both rf MFMAs; both cf of a row merge online -> 8 (M,S)
// slots/lane. k-tiles (16 KiB) TRIPLE-buffered, XOR-swizzled (R6 formulas).
__launch_bounds__(256, 2)
__global__ void sim_lse_kernel(const _Float16* __restrict__ qh,
                               const _Float16* __restrict__ kh,
                               float* __restrict__ pM,
                               float* __restrict__ pS) {
  __shared__ __align__(16) _Float16 kt[NBUF * BN * C_DIM];  // 48 KiB
  const int tid  = threadIdx.x;
  const int lane = tid & 63;
  const int wave = tid >> 6;
  const int l15  = lane & 15;
  const int lg   = lane >> 4;       // quad group 0..3

  const int bid  = blockIdx.x;
  const int sp   = bid & (SPLIT - 1);
  const int rb   = bid >> 4;
  const int row0 = rb * BLK_ROWS + wave * 32;

  // A fragments resident for whole kernel: 2 x 8 x half8 = 64 VGPR
  half8 a[2][8];
#pragma unroll
  for (int rf = 0; rf < 2; ++rf) {
    const _Float16* qr = qh + (size_t)(row0 + rf * 16 + l15) * C_DIM + lg * 8;
#pragma unroll
    for (int ks = 0; ks < 8; ++ks) a[rf][ks] = *(const half8*)(qr + ks * 32);
  }

  // Per-lane LSE state: slot s = rf*4 + j  ->  row = row0 + rf*16 + lg*4 + j
  float M[8], S[8];
#pragma unroll
  for (int s = 0; s < 8; ++s) { M[s] = -__builtin_inff(); S[s] = 0.f; }

  // swizzled LDS read base per col-frag (R0/R6-verified): read bb ^ (ks*64)
  const int nl0 = l15;            // cf = 0
  const int nl1 = 16 + l15;       // cf = 1
  const int bb0 = nl0 * 512 + (((nl0 & 31) * 16) ^ (lg * 16));
  const int bb1 = nl1 * 512 + (((nl1 & 31) * 16) ^ (lg * 16));

  const char* ksrc = (const char*)(kh + (size_t)sp * JCOLS * C_DIM);
  char* lds = (char*)kt;

  // ---- staging macro body: 4 x global_load_lds of 16 B per thread ---------
  // (swizzled global source, linear LDS dest; R6-verified formulas)
#define STAGE(t, bufidx)                                                     \
  do {                                                                       \
    const char* _src = ksrc + (size_t)(t) * TILE_B;                          \
    char* _dst = lds + (bufidx) * TILE_B;                                    \
    _Pragma("unroll")                                                        \
    for (int _it = 0; _it < 4; ++_it) {                                      \
      int _lin = _it * 4096 + tid * 16;                                      \
      int _row = _lin >> 9;                                                  \
      int _gc  = ((_lin >> 4) & 31) ^ (_row & 31);                           \
      gload_lds16(_src + _row * 512 + _gc * 16, _dst + _lin);                \
    }                                                                        \
  } while (0)

  // ---- prologue: stage tiles 0 and 1 --------------------------------------
  STAGE(0, 0);
  STAGE(1, 1);

  int cb = 0;                      // cur buffer = jt % 3 (tracked incrementally)
  for (int jt = 0; jt < JTILES; ++jt) {
    // wait for stage(jt): 4 loads/stage, oldest retire first (m135), so
    // vmcnt(4) leaves stage(jt+1)'s 4 loads in flight across the barrier.
    if (jt < JTILES - 1) {
      asm volatile("s_waitcnt vmcnt(4)" ::: "memory");
    } else {
      asm volatile("s_waitcnt vmcnt(0)" ::: "memory");
    }
    __builtin_amdgcn_sched_barrier(0);   // rule #18: no hoisting across wait
    __builtin_amdgcn_s_barrier();        // raw barrier: NO vmcnt(0) drain

    // stage(jt+2) into buf[(jt+2)%3] = buf[(jt-1)%3]; all waves proved done
    // reading that buffer by the barrier above.
    if (jt + 2 < JTILES) {
      int nb = cb + 2; if (nb >= NBUF) nb -= NBUF;
      STAGE(jt + 2, nb);
    }

    const char* cur = lds + cb * TILE_B;

    // ---- 32-col tile: 8 K-steps x {2 col-frags x 2 row-frags} MFMA --------
    f32x4 acc00 = {0.f,0.f,0.f,0.f}, acc01 = {0.f,0.f,0.f,0.f};
    f32x4 acc10 = {0.f,0.f,0.f,0.f}, acc11 = {0.f,0.f,0.f,0.f};

#pragma unroll
    for (int ks = 0; ks < 8; ++ks) {
      half8 b0 = *(const half8*)(cur + (bb0 ^ (ks * 64)));
      half8 b1 = *(const half8*)(cur + (bb1 ^ (ks * 64)));
      acc00 = __builtin_amdgcn_mfma_f32_16x16x32_f16(a[0][ks], b0, acc00, 0, 0, 0);
      acc01 = __builtin_amdgcn_mfma_f32_16x16x32_f16(a[0][ks], b1, acc01, 0, 0, 0);
      acc10 = __builtin_amdgcn_mfma_f32_16x16x32_f16(a[1][ks], b0, acc10, 0, 0, 0);
      acc11 = __builtin_amdgcn_mfma_f32_16x16x32_f16(a[1][ks], b1, acc11, 0, 0, 0);
    }

    // ---- per-lane online logsumexp: merge the row's two cols in one step --
#pragma unroll
    for (int j = 0; j < 4; ++j) {
      {  // rf = 0, slot j
        float v0 = acc00[j], v1 = acc01[j];
        float newM  = fmaxf(M[j], fmaxf(v0, v1));
        float alpha = EXP2(M[j] - newM);      // exp2(-inf)=0 handles init
        float p = EXP2(v0 - newM) + EXP2(v1 - newM);
        S[j] = fmaf(S[j], alpha, p);
        M[j] = newM;
      }
      {  // rf = 1, slot 4 + j
        float v0 = acc10[j], v1 = acc11[j];
        float newM  = fmaxf(M[4 + j], fmaxf(v0, v1));
        float alpha = EXP2(M[4 + j] - newM);
        float p = EXP2(v0 - newM) + EXP2(v1 - newM);
        S[4 + j] = fmaf(S[4 + j], alpha, p);
        M[4 + j] = newM;
      }
    }

    // NOTE: no trailing barrier needed — next iteration's barrier (after its
    // vmcnt wait) provides the read-done guarantee before buffer reuse.
    ++cb; if (cb >= NBUF) cb -= NBUF;
  }
#undef STAGE

  // ---- one-time 16-lane butterfly merge of (M,S) --------------------------
#pragma unroll
  for (int s = 0; s < 8; ++s) {
#pragma unroll
    for (int off = 1; off < 16; off <<= 1) {
      float Mo = __shfl_xor(M[s], off);
      float So = __shfl_xor(S[s], off);
      float nm = fmaxf(M[s], Mo);
      S[s] = S[s] * EXP2(M[s] - nm) + So * EXP2(Mo - nm);
      M[s] = nm;
    }
  }

  if (l15 == 0) {   // 4 lanes per wave (lg = 0..3), 8 rows each = 32 rows
#pragma unroll
    for (int s = 0; s < 8; ++s) {
      int grow = row0 + (s >> 2) * 16 + lg * 4 + (s & 3);
      pM[(size_t)sp * N_ROWS + grow] = M[s];
      pS[(size_t)sp * N_ROWS + grow] = S[s];
    }
  }
}

// ---- stage 1: 32 blocks, one thread per row; partial sums -----------------
__global__ void finish1_kernel(const float* __restrict__ pM, const float* __restrict__ pS,
                               const float* __restrict__ pP, float* __restrict__ pPart) {
  const int tid = threadIdx.x;
  const int r = blockIdx.x * 256 + tid;
  float m = -__builtin_inff();
#pragma unroll
  for (int s = 0; s < SPLIT; ++s) m = fmaxf(m, pM[s * N_ROWS + r]);
  float ssum = 0.f;
#pragma unroll
  for (int s = 0; s < SPLIT; ++s)
    ssum = fmaf(pS[s * N_ROWS + r], EXP2(pM[s * N_ROWS + r] - m), ssum);
  float accl = (m + LOG2(ssum)) - pP[r];   // row loss in base-2 units
#pragma unroll
  for (int off = 1; off < 64; off <<= 1) accl += __shfl_xor(accl, off);
  __shared__ float wsum[4];
  if ((tid & 63) == 0) wsum[tid >> 6] = accl;
  __syncthreads();
  if (tid == 0)
    pPart[blockIdx.x] = wsum[0] + wsum[1] + wsum[2] + wsum[3];
}

// ---- stage 2: reduce 32 partials, convert base-2 -> nats, mean ------------
__global__ void finish2_kernel(const float* __restrict__ pPart, float* __restrict__ out) {
  const int tid = threadIdx.x;   // 64 threads
  float v = (tid < 32) ? pPart[tid] : 0.f;
#pragma unroll
  for (int off = 1; off < 64; off <<= 1) v += __shfl_xor(v, off);
  if (tid == 0)
    out[0] = v * (0.69314718055994531f / (float)N_ROWS);  // ln2 * mean
}

extern "C" void kernel_launch(void* const* d_in, const int* in_sizes, int n_in,
                              void* d_out, int out_size, void* d_ws, size_t ws_size,
                              hipStream_t stream) {
  const float* q = (const float*)d_in[0];
  const float* k = (const float*)d_in[1];
  float* out = (float*)d_out;
  char* ws = (char*)d_ws;

  _Float16* qh = (_Float16*)ws;                                  // 4 MiB
  _Float16* kh = (_Float16*)(ws + (size_t)N_ROWS * C_DIM * 2);   // 4 MiB
  float* pM = (float*)(ws + (size_t)N_ROWS * C_DIM * 4);         // 512 KiB
  float* pS = pM + SPLIT * N_ROWS;                               // 512 KiB
  float* pP = pS + SPLIT * N_ROWS;                               // 32 KiB
  float* pPart = pP + N_ROWS;                                    // 128 B

  cvt_kernel<<<dim3(N_ROWS * C_DIM / 4 / 256), dim3(256), 0, stream>>>(q, k, qh, kh, pP);
  sim_lse_kernel<<<dim3((N_ROWS / BLK_ROWS) * SPLIT), dim3(256), 0, stream>>>(qh, kh, pM, pS);
  finish1_kernel<<<dim3(N_ROWS / 256), dim3(256), 0, stream>>>(pM, pS, pP, pPart);
  finish2_kernel<<<dim3(1), dim3(64), 0, stream>>>(pPart, out);
}